// Round 10
// baseline (616.467 us; speedup 1.0000x reference)
//
#include <hip/hip_runtime.h>
#include <hip/hip_fp16.h>

#define NLAYERS 5

struct alignas(8) H4 { __half h[4]; };

typedef _Float16 half2_t __attribute__((ext_vector_type(2)));
typedef float f32x4 __attribute__((ext_vector_type(4)));

#if defined(__has_builtin)
#if __has_builtin(__builtin_amdgcn_fdot2)
#define HAS_FDOT2 1
#endif
#endif

// ---------------- setup kernels ----------------
// one thread per edge: deg histogram + rank. cnt histogram wave-aggregated:
// batch is sorted, so each wave spans 1-3 graphs; one atomic per run-leader
// instead of 64 same-address atomics (those serialize ~100 deep).
__global__ void k_rank(const int* __restrict__ ei, int E, int* __restrict__ deg,
                       int* __restrict__ rank, const int* __restrict__ batch, int N,
                       int* __restrict__ cnt) {
    int t = threadIdx.x;
    int i = blockIdx.x * 256 + t;
    int lane = t & 63;
    if (i < E) {
        int s = ei[i], d = ei[E + i];
        rank[i] = (s != d) ? atomicAdd(&deg[d], 1) : -1;
    }
    bool valid = (i < N);
    int b = valid ? batch[i] : -1;
    int prevb = __shfl_up(b, 1);
    bool leader = valid && ((lane == 0) || (prevb != b));
    unsigned long long lm = __ballot(leader);
    unsigned long long am = __ballot(valid);
    if (leader) {
        unsigned long long above = (lane < 63) ? (lm >> (lane + 1)) : 0ULL;
        int next = above ? (lane + 1 + (__ffsll((long long)above) - 1)) : 64;
        int nact = __popcll(am);   // valid lanes form a prefix
        if (next > nact) next = nact;
        atomicAdd(&cnt[b], next - lane);
    }
}

// hierarchical scan: bsum -> bscan (1 block) -> rowptr
__global__ void k_bsum(const int* __restrict__ deg, int N, int* __restrict__ bsum) {
    __shared__ int sh[256];
    int t = threadIdx.x, i = blockIdx.x * 256 + t;
    sh[t] = (i < N) ? deg[i] : 0;
    __syncthreads();
    for (int o = 128; o > 0; o >>= 1) {
        if (t < o) sh[t] += sh[t + o];
        __syncthreads();
    }
    if (t == 0) bsum[blockIdx.x] = sh[0];
}

__global__ void k_bscan(const int* __restrict__ bsum, int P, int* __restrict__ boff,
                        int* __restrict__ rowptr, int N) {
    __shared__ int sh[256];
    int t = threadIdx.x;
    int v = (t < P) ? bsum[t] : 0;
    sh[t] = v;
    __syncthreads();
    for (int o = 1; o < 256; o <<= 1) {
        int u = (t >= o) ? sh[t - o] : 0;
        __syncthreads();
        sh[t] += u;
        __syncthreads();
    }
    if (t < P) boff[t] = sh[t] - v;      // exclusive
    if (t == 255) rowptr[N] = sh[255];   // total non-self edges
}

__global__ void k_rowptr(const int* __restrict__ deg, const int* __restrict__ boff, int N,
                         int* __restrict__ rowptr) {
    __shared__ int sh[256];
    int t = threadIdx.x, i = blockIdx.x * 256 + t;
    int v = (i < N) ? deg[i] : 0;
    sh[t] = v;
    __syncthreads();
    for (int o = 1; o < 256; o <<= 1) {
        int u = (t >= o) ? sh[t - o] : 0;
        __syncthreads();
        sh[t] += u;
        __syncthreads();
    }
    int ex = sh[t] - v + boff[blockIdx.x];
    if (i < N) rowptr[i] = ex;
}

// place edges without atomics: csr_eid[rowptr[d] + rank[e]] = e
__global__ void k_scatter2(const int* __restrict__ ei, const int* __restrict__ rank,
                           const int* __restrict__ rowptr, int E, int* __restrict__ csr_eid) {
    int e = blockIdx.x * blockDim.x + threadIdx.x;
    if (e >= E) return;
    int r = rank[e];
    if (r >= 0) {
        int d = ei[E + e];
        csr_eid[rowptr[d] + r] = e;
    }
}

// gather-permute: coalesced writes of csr_src + eaPerm(f16), random reads (L2/L3-served)
__global__ void k_permute(const int* __restrict__ csr_eid, const int* __restrict__ ei,
                          const float* __restrict__ edge_attr, const int* __restrict__ EnPtr,
                          int* __restrict__ csr_src, __half* __restrict__ eaPerm, int E) {
    int En = EnPtr[0];
    int j = blockIdx.x * blockDim.x + threadIdx.x;
    if (j >= En) return;
    int eid = csr_eid[j];
    csr_src[j] = ei[eid];
    const float4* ea4 = (const float4*)(edge_attr + (size_t)eid * 16);
    float4 a = ea4[0], b = ea4[1], c = ea4[2], dd = ea4[3];
    union { __half h[8]; float4 f; } u0, u1;
    u0.h[0] = __float2half(a.x); u0.h[1] = __float2half(a.y);
    u0.h[2] = __float2half(a.z); u0.h[3] = __float2half(a.w);
    u0.h[4] = __float2half(b.x); u0.h[5] = __float2half(b.y);
    u0.h[6] = __float2half(b.z); u0.h[7] = __float2half(b.w);
    u1.h[0] = __float2half(c.x); u1.h[1] = __float2half(c.y);
    u1.h[2] = __float2half(c.z); u1.h[3] = __float2half(c.w);
    u1.h[4] = __float2half(dd.x); u1.h[5] = __float2half(dd.y);
    u1.h[6] = __float2half(dd.z); u1.h[7] = __float2half(dd.w);
    float4* out = (float4*)(eaPerm + (size_t)j * 16);
    out[0] = u0.f; out[1] = u1.f;
}

// 4x4 micro-tile GEMM; AT transposed in LDS (given stride), W row-major in LDS.
template <int STRIDE>
__device__ __forceinline__ void gemm_tile(const float* AT, const float* W, float acc[4][4], int ty, int tx) {
    #pragma unroll
    for (int i = 0; i < 4; i++)
        #pragma unroll
        for (int j = 0; j < 4; j++) acc[i][j] = 0.f;
    #pragma unroll 4
    for (int k = 0; k < 64; k++) {
        const float4 a4 = *(const float4*)(AT + k * STRIDE + ty * 4);
        const float4 b4 = *(const float4*)(W + k * 64 + tx * 4);
        float a[4] = {a4.x, a4.y, a4.z, a4.w};
        float b[4] = {b4.x, b4.y, b4.z, b4.w};
        #pragma unroll
        for (int i = 0; i < 4; i++)
            #pragma unroll
            for (int j = 0; j < 4; j++) acc[i][j] += a[i] * b[j];
    }
}

// Standalone prep kernel (no LDS tax on rank):
//  blocks 0..4  : P[l], pb[l];  5..8: Q[l], qb[l];  9..12: R[l], rb[l]
//  blocks 13..17: Wpack[l];  blocks 18..: layer-0 node GEMMs
__global__ void k_prep(const float* __restrict__ X,
                       const float* nn2_w1, const float* nn2_w2, const float* nn2_b2,
                       const float* nn1_w1, const float* nn1_w2, const float* nn1_b2,
                       float* P, float* pb, float* Q, float* qb, float* R, float* rb,
                       __half2* Wpack, __half* __restrict__ xW1, float* __restrict__ xA0,
                       int N) {
    __shared__ float XT[64 * 68];
    __shared__ float W[64 * 64];
    int job = blockIdx.x;
    int t = threadIdx.x;
    if (job >= 13 && job < 18) {
        int l = job - 13;
        const float* Wm = nn2_w1 + (size_t)l * 5120 + 64 * 64;
        for (int i = 0; i < 2; i++) {
            int t2 = t + i * 256;
            int p = t2 >> 6, lane = t2 & 63;
            float a = Wm[(2 * p) * 64 + lane];
            float b = Wm[(2 * p + 1) * 64 + lane];
            Wpack[l * 512 + t2] = __halves2half2(__float2half(a), __float2half(b));
        }
        return;
    }
    if (job < 13) {
        const float* left; const float* lb; const float* right; float* out; float* ob;
        if (job < 5) {
            int l = job;
            left = nn2_w2 + l * 4096; lb = nn2_b2 + l * 64; right = nn1_w1 + l * 4096;
            out = P + l * 4096; ob = pb + l * 64;
        } else if (job < 9) {
            int l = job - 5;
            left = nn1_w2 + l * 4096; lb = nn1_b2 + l * 64; right = nn2_w1 + (l + 1) * 5120;
            out = Q + l * 4096; ob = qb + l * 64;
        } else {
            int l = job - 9;
            left = nn1_w2 + l * 4096; lb = nn1_b2 + l * 64; right = nn1_w1 + (l + 1) * 4096;
            out = R + l * 4096; ob = rb + l * 64;
        }
        int r0 = (t >> 4) * 4, c0 = (t & 15) * 4;
        float acc[4][4] = {};
        for (int k = 0; k < 64; k++) {
            float b[4];
            #pragma unroll
            for (int j = 0; j < 4; j++) b[j] = right[k * 64 + c0 + j];
            #pragma unroll
            for (int i = 0; i < 4; i++) {
                float a = left[(r0 + i) * 64 + k];
                #pragma unroll
                for (int j = 0; j < 4; j++) acc[i][j] += a * b[j];
            }
        }
        for (int i = 0; i < 4; i++)
            for (int j = 0; j < 4; j++)
                out[(r0 + i) * 64 + c0 + j] = acc[i][j];
        if (t < 64) {
            float s = 0.f;
            for (int k = 0; k < 64; k++) s += lb[k] * right[k * 64 + t];
            ob[t] = s;
        }
        return;
    }
    // layer-0 node GEMMs: xW1(f16) = x@Wx0, xA0(f32) = x@A0
    int ty = t >> 4, tx = t & 15;
    int base = (job - 18) * 64;
    for (int q = 0; q < 4; q++) {
        int row = ty + q * 16;
        int gr = base + row;
        float4 v = make_float4(0.f, 0.f, 0.f, 0.f);
        if (gr < N) v = *(const float4*)(X + (size_t)gr * 64 + tx * 4);
        XT[(tx * 4 + 0) * 68 + row] = v.x;
        XT[(tx * 4 + 1) * 68 + row] = v.y;
        XT[(tx * 4 + 2) * 68 + row] = v.z;
        XT[(tx * 4 + 3) * 68 + row] = v.w;
    }
    for (int q = 0; q < 4; q++) ((float4*)W)[t + q * 256] = ((const float4*)nn2_w1)[t + q * 256];
    __syncthreads();
    float acc[4][4];
    gemm_tile<68>(XT, W, acc, ty, tx);
    for (int i = 0; i < 4; i++) {
        int gr = base + ty * 4 + i;
        if (gr < N) {
            H4 o;
            o.h[0] = __float2half(acc[i][0]); o.h[1] = __float2half(acc[i][1]);
            o.h[2] = __float2half(acc[i][2]); o.h[3] = __float2half(acc[i][3]);
            *(H4*)(xW1 + (size_t)gr * 64 + tx * 4) = o;
        }
    }
    __syncthreads();
    for (int q = 0; q < 4; q++) ((float4*)W)[t + q * 256] = ((const float4*)nn1_w1)[t + q * 256];
    __syncthreads();
    gemm_tile<68>(XT, W, acc, ty, tx);
    for (int i = 0; i < 4; i++) {
        int gr = base + ty * 4 + i;
        if (gr < N) {
            float4 o = make_float4(acc[i][0], acc[i][1], acc[i][2], acc[i][3]);
            *(float4*)(xA0 + (size_t)gr * 64 + tx * 4) = o;
        }
    }
}

// Edge phase: one wave per destination node, lane = channel. Chunk of 16 edges.
// csr_src/eaPerm are zero-reuse streams -> non-temporal loads keep L2 for xW1.
__global__ __launch_bounds__(256, 8) void k_edge(
        const int* __restrict__ rowptr, const int* __restrict__ csr_src,
        const __half* __restrict__ eaPerm, const __half* __restrict__ xW1,
        const __half2* __restrict__ Wpack, const float* __restrict__ b1m,
        float* __restrict__ Hsum, int N) {
    __shared__ __align__(16) char eaL[4][16 * 32];
    int t = threadIdx.x;
    int wave = t >> 6, lane = t & 63;
    int wid = __builtin_amdgcn_readfirstlane(blockIdx.x * 4 + wave);
    if (wid >= N) return;
    half2_t w[8];
    const unsigned int* wp = (const unsigned int*)Wpack;
    #pragma unroll
    for (int p = 0; p < 8; p++) w[p] = __builtin_bit_cast(half2_t, wp[p * 64 + lane]);
    float b1 = b1m[lane];
    int beg = __builtin_amdgcn_readfirstlane(rowptr[wid]);
    int end = __builtin_amdgcn_readfirstlane(rowptr[wid + 1]);
    float acc = 0.f;
    for (int cbeg = beg; cbeg < end; cbeg += 16) {
        int m = end - cbeg; m = (m < 16) ? m : 16;
        int srcv = 0;
        if (lane < 16) {
            int ii = (lane < m) ? lane : (m - 1);
            srcv = __builtin_nontemporal_load(csr_src + cbeg + ii);
        } else if (lane >= 32) {
            int l2 = lane - 32;
            int eidx = l2 >> 1;
            int ii = (eidx < m) ? eidx : (m - 1);
            const f32x4* ep = (const f32x4*)((const char*)eaPerm + ((size_t)(cbeg + ii) << 5) + ((size_t)(l2 & 1) << 4));
            f32x4 v = __builtin_nontemporal_load(ep);
            *(f32x4*)(&eaL[wave][l2 << 4]) = v;
        }
        __half xv[16];
        #pragma unroll
        for (int i = 0; i < 16; i++) {
            int s = __builtin_amdgcn_readlane(srcv, i);
            xv[i] = xW1[(size_t)s * 64 + lane];
        }
        #pragma unroll
        for (int i = 0; i < 16; i++) {
            const half2_t* e8 = (const half2_t*)(&eaL[wave][i << 5]);
            float d = __half2float(xv[i]) + b1;
#ifdef HAS_FDOT2
            #pragma unroll
            for (int p = 0; p < 8; p++) d = __builtin_amdgcn_fdot2(e8[p], w[p], d, false);
#else
            half2_t s0 = e8[0] * w[0] + e8[1] * w[1];
            #pragma unroll
            for (int p = 2; p < 8; p += 2) s0 = e8[p] * w[p] + e8[p + 1] * w[p + 1] + s0;
            d += (float)s0[0] + (float)s0[1];
#endif
            acc += (i < m) ? fmaxf(d, 0.f) : 0.f;
        }
    }
    Hsum[(size_t)wid * 64 + lane] = acc;
}

// Node phase for layer l (64-node tiles, AT reused for HT).
// Pooled readout LDS-pre-reduced (batch sorted, tile spans few graphs).
__global__ void k_node(const float* __restrict__ Hsum, const float* __restrict__ xA,
                       const int* __restrict__ deg, const int* __restrict__ batch,
                       const float* __restrict__ P, const float* __restrict__ pb,
                       const float* __restrict__ a_l, const float* __restrict__ epsp,
                       const float* __restrict__ Q, const float* __restrict__ qb,
                       __half* __restrict__ out1,
                       const float* __restrict__ R, const float* __restrict__ rb,
                       float* __restrict__ out2,
                       float* __restrict__ hpool_l, int N, int has_next) {
    __shared__ float AT[64 * 68];   // Hsum^T, later reused as HT
    __shared__ float W[64 * 64];
    __shared__ float shp[8 * 64];   // local pool tile (up to 8 graphs)
    int t = threadIdx.x, ty = t >> 4, tx = t & 15;
    int base = blockIdx.x * 64;
    int lastn = base + 63; if (lastn > N - 1) lastn = N - 1;
    int gmin = batch[base];
    int span = batch[lastn] - gmin + 1;
    if (span <= 8) {
        for (int q = t; q < span * 64; q += 256) shp[q] = 0.f;
    }
    for (int q = 0; q < 4; q++) {
        int row = ty + q * 16;
        int gr = base + row;
        float4 v = make_float4(0.f, 0.f, 0.f, 0.f);
        if (gr < N) v = *(const float4*)(Hsum + (size_t)gr * 64 + tx * 4);
        AT[(tx * 4 + 0) * 68 + row] = v.x;
        AT[(tx * 4 + 1) * 68 + row] = v.y;
        AT[(tx * 4 + 2) * 68 + row] = v.z;
        AT[(tx * 4 + 3) * 68 + row] = v.w;
    }
    for (int q = 0; q < 4; q++) ((float4*)W)[t + q * 256] = ((const float4*)P)[t + q * 256];
    __syncthreads();
    float acc[4][4];
    gemm_tile<68>(AT, W, acc, ty, tx);
    float eps1 = 1.f + epsp[0];
    float4 pbv = *(const float4*)(pb + tx * 4);
    float4 av = *(const float4*)(a_l + tx * 4);
    float h[4][4];
    int gidx[4];
    for (int i = 0; i < 4; i++) {
        int gr = base + ty * 4 + i;
        float dg = 0.f;
        float4 xa = make_float4(0.f, 0.f, 0.f, 0.f);
        if (gr < N) {
            dg = (float)deg[gr];
            xa = *(const float4*)(xA + (size_t)gr * 64 + tx * 4);
            gidx[i] = batch[gr];
        } else {
            gidx[i] = -1;
        }
        h[i][0] = fmaxf(acc[i][0] + eps1 * xa.x + dg * pbv.x + av.x, 0.f);
        h[i][1] = fmaxf(acc[i][1] + eps1 * xa.y + dg * pbv.y + av.y, 0.f);
        h[i][2] = fmaxf(acc[i][2] + eps1 * xa.z + dg * pbv.z + av.z, 0.f);
        h[i][3] = fmaxf(acc[i][3] + eps1 * xa.w + dg * pbv.w + av.w, 0.f);
    }
    if (span <= 8) {
        #pragma unroll
        for (int j = 0; j < 4; j++) {
            int i = 0;
            while (i < 4) {
                if (gidx[i] < 0) { i++; continue; }
                int g = gidx[i];
                float s = h[i][j];
                int k2 = i + 1;
                while (k2 < 4 && gidx[k2] == g) { s += h[k2][j]; k2++; }
                atomicAdd(&shp[(g - gmin) * 64 + tx * 4 + j], s);
                i = k2;
            }
        }
        __syncthreads();
        for (int q = t; q < span * 64; q += 256) {
            float v = shp[q];
            if (v != 0.f) atomicAdd(&hpool_l[(gmin + (q >> 6)) * 64 + (q & 63)], v);
        }
    } else {
        #pragma unroll
        for (int j = 0; j < 4; j++) {
            int i = 0;
            while (i < 4) {
                if (gidx[i] < 0) { i++; continue; }
                int g = gidx[i];
                float s = h[i][j];
                int k2 = i + 1;
                while (k2 < 4 && gidx[k2] == g) { s += h[k2][j]; k2++; }
                atomicAdd(&hpool_l[g * 64 + tx * 4 + j], s);
                i = k2;
            }
        }
    }
    if (has_next) {
        __syncthreads();  // all reads of AT done — safe to overwrite with HT
        for (int i = 0; i < 4; i++)
            for (int j = 0; j < 4; j++)
                AT[(tx * 4 + j) * 68 + ty * 4 + i] = h[i][j];
        for (int q = 0; q < 4; q++) ((float4*)W)[t + q * 256] = ((const float4*)Q)[t + q * 256];
        __syncthreads();
        gemm_tile<68>(AT, W, acc, ty, tx);
        float4 qbv = *(const float4*)(qb + tx * 4);
        for (int i = 0; i < 4; i++) {
            int gr = base + ty * 4 + i;
            if (gr < N) {
                H4 o;
                o.h[0] = __float2half(acc[i][0] + qbv.x);
                o.h[1] = __float2half(acc[i][1] + qbv.y);
                o.h[2] = __float2half(acc[i][2] + qbv.z);
                o.h[3] = __float2half(acc[i][3] + qbv.w);
                *(H4*)(out1 + (size_t)gr * 64 + tx * 4) = o;
            }
        }
        __syncthreads();
        for (int q = 0; q < 4; q++) ((float4*)W)[t + q * 256] = ((const float4*)R)[t + q * 256];
        __syncthreads();
        gemm_tile<68>(AT, W, acc, ty, tx);
        float4 rbv = *(const float4*)(rb + tx * 4);
        for (int i = 0; i < 4; i++) {
            int gr = base + ty * 4 + i;
            if (gr < N) {
                float4 o = make_float4(acc[i][0] + rbv.x, acc[i][1] + rbv.y,
                                       acc[i][2] + rbv.z, acc[i][3] + rbv.w);
                *(float4*)(out2 + (size_t)gr * 64 + tx * 4) = o;
            }
        }
    }
}

// fused readout: feats then final MLP
__global__ void k_pool_final(const float* __restrict__ hpool, const int* __restrict__ cnt,
                             const float* __restrict__ nn1_w2, const float* __restrict__ nn1_b2,
                             const float* __restrict__ F1, const float* __restrict__ fb1,
                             const float* __restrict__ F2, const float* __restrict__ fb2,
                             float* __restrict__ out, int G) {
    int g = blockIdx.x;
    int c = threadIdx.x; // 320
    int l = c >> 6, cc = c & 63;
    const float* hp = hpool + ((size_t)l * G + g) * 64;
    const float* B = nn1_w2 + l * 4096;
    float s = (float)cnt[g] * nn1_b2[l * 64 + cc];
    for (int k = 0; k < 64; k++) s += hp[k] * B[k * 64 + cc];
    __shared__ float sh1[320];
    __shared__ float sh2[320];
    sh1[c] = s;
    __syncthreads();
    float t2 = fb1[c];
    for (int k = 0; k < 320; k++) t2 += sh1[k] * F1[k * 320 + c];
    t2 = fmaxf(t2, 0.f);
    sh2[c] = t2 * F2[c];
    __syncthreads();
    if (c == 0) {
        float y = fb2[0];
        for (int k = 0; k < 320; k++) y += sh2[k];
        out[g] = y;
    }
}

extern "C" void kernel_launch(void* const* d_in, const int* in_sizes, int n_in,
                              void* d_out, int out_size, void* d_ws, size_t ws_size,
                              hipStream_t stream) {
    const float* x        = (const float*)d_in[0];
    const int*   ei       = (const int*)d_in[1];
    const float* edge_attr= (const float*)d_in[2];
    const int*   batch    = (const int*)d_in[3];
    const float* nn2_w1   = (const float*)d_in[4];
    const float* nn2_b1   = (const float*)d_in[5];
    const float* nn2_w2   = (const float*)d_in[6];
    const float* nn2_b2   = (const float*)d_in[7];
    const float* nn1_w1   = (const float*)d_in[8];
    const float* nn1_b1   = (const float*)d_in[9];
    const float* nn1_w2   = (const float*)d_in[10];
    const float* nn1_b2   = (const float*)d_in[11];
    const float* fin_w1   = (const float*)d_in[12];
    const float* fin_b1   = (const float*)d_in[13];
    const float* fin_w2   = (const float*)d_in[14];
    const float* fin_b2   = (const float*)d_in[15];
    const float* eps      = (const float*)d_in[16];

    int N = in_sizes[0] / 64;
    int E = in_sizes[1] / 2;
    int G = out_size;

    char* p = (char*)d_ws;
    auto alloc = [&](size_t bytes) -> char* {
        char* r = p;
        p += (bytes + 255) & ~(size_t)255;
        return r;
    };
    int*    deg     = (int*)alloc((size_t)N * 4);
    int*    cnt     = (int*)alloc((size_t)G * 4);
    int*    rowptr  = (int*)alloc((size_t)(N + 1) * 4);
    int*    rank    = (int*)alloc((size_t)E * 4);
    int*    bsum    = (int*)alloc(256 * 4);
    int*    boff    = (int*)alloc(256 * 4);
    int*    csr_eid = (int*)alloc((size_t)E * 4);
    int*    csr_src = (int*)alloc((size_t)E * 4 + 256);
    __half* eaPerm  = (__half*)alloc((size_t)E * 16 * 2 + 1024);
    __half* xW1     = (__half*)alloc((size_t)N * 64 * 2);
    float*  xA0     = (float*)alloc((size_t)N * 64 * 4);
    float*  xA1     = (float*)alloc((size_t)N * 64 * 4);
    float*  Hsum    = (float*)alloc((size_t)N * 64 * 4);
    float*  hpool   = (float*)alloc((size_t)NLAYERS * G * 64 * 4);
    float*  P       = (float*)alloc(5 * 4096 * 4);
    float*  pb      = (float*)alloc(5 * 64 * 4);
    float*  Q       = (float*)alloc(4 * 4096 * 4);
    float*  qb      = (float*)alloc(4 * 64 * 4);
    float*  R       = (float*)alloc(4 * 4096 * 4);
    float*  rb      = (float*)alloc(4 * 64 * 4);
    __half2* Wpack  = (__half2*)alloc(5 * 512 * 4);

    hipMemsetAsync(deg, 0, (size_t)N * 4, stream);
    hipMemsetAsync(cnt, 0, (size_t)G * 4, stream);
    hipMemsetAsync(hpool, 0, (size_t)NLAYERS * G * 64 * 4, stream);

    int Pblk = (N + 255) / 256;  // <= 256
    int nb64 = (N + 63) / 64;
    int EB = (E + 255) / 256;
    k_rank<<<EB, 256, 0, stream>>>(ei, E, deg, rank, batch, N, cnt);
    k_prep<<<18 + nb64, 256, 0, stream>>>(x, nn2_w1, nn2_w2, nn2_b2, nn1_w1, nn1_w2, nn1_b2,
                                          P, pb, Q, qb, R, rb, Wpack, xW1, xA0, N);
    k_bsum<<<Pblk, 256, 0, stream>>>(deg, N, bsum);
    k_bscan<<<1, 256, 0, stream>>>(bsum, Pblk, boff, rowptr, N);
    k_rowptr<<<Pblk, 256, 0, stream>>>(deg, boff, N, rowptr);
    k_scatter2<<<EB, 256, 0, stream>>>(ei, rank, rowptr, E, csr_eid);
    k_permute<<<EB, 256, 0, stream>>>(csr_eid, ei, edge_attr, rowptr + N, csr_src, eaPerm, E);

    float* xA_cur = xA0;
    float* xA_nxt = xA1;
    int eblocks = (N + 3) / 4; // 4 waves/block, one wave per node
    for (int l = 0; l < NLAYERS; l++) {
        int has_next = (l < NLAYERS - 1) ? 1 : 0;
        k_edge<<<eblocks, 256, 0, stream>>>(rowptr, csr_src, eaPerm, xW1,
                                            Wpack + l * 512, nn2_b1 + l * 64, Hsum, N);
        k_node<<<nb64, 256, 0, stream>>>(Hsum, xA_cur, deg, batch,
                                         P + l * 4096, pb + l * 64, nn1_b1 + l * 64, eps,
                                         Q + (has_next ? l : 0) * 4096, qb + (has_next ? l : 0) * 64, xW1,
                                         R + (has_next ? l : 0) * 4096, rb + (has_next ? l : 0) * 64, xA_nxt,
                                         hpool + (size_t)l * G * 64, N, has_next);
        float* tmp = xA_cur; xA_cur = xA_nxt; xA_nxt = tmp;
    }

    k_pool_final<<<G, 320, 0, stream>>>(hpool, cnt, nn1_w2, nn1_b2,
                                        fin_w1, fin_b1, fin_w2, fin_b2, (float*)d_out, G);
}

// Round 11
// 583.812 us; speedup vs baseline: 1.0559x; 1.0559x over previous
//
#include <hip/hip_runtime.h>
#include <hip/hip_fp16.h>

#define NLAYERS 5

struct alignas(8) H4 { __half h[4]; };

typedef _Float16 f16x8 __attribute__((ext_vector_type(8)));
typedef _Float16 f16x4 __attribute__((ext_vector_type(4)));
typedef float f32x4v __attribute__((ext_vector_type(4)));

// ---------------- setup kernels ----------------
// one thread per edge: deg histogram + rank. cnt histogram wave-aggregated.
__global__ void k_rank(const int* __restrict__ ei, int E, int* __restrict__ deg,
                       int* __restrict__ rank, const int* __restrict__ batch, int N,
                       int* __restrict__ cnt) {
    int t = threadIdx.x;
    int i = blockIdx.x * 256 + t;
    int lane = t & 63;
    if (i < E) {
        int s = ei[i], d = ei[E + i];
        rank[i] = (s != d) ? atomicAdd(&deg[d], 1) : -1;
    }
    bool valid = (i < N);
    int b = valid ? batch[i] : -1;
    int prevb = __shfl_up(b, 1);
    bool leader = valid && ((lane == 0) || (prevb != b));
    unsigned long long lm = __ballot(leader);
    unsigned long long am = __ballot(valid);
    if (leader) {
        unsigned long long above = (lane < 63) ? (lm >> (lane + 1)) : 0ULL;
        int next = above ? (lane + 1 + (__ffsll((long long)above) - 1)) : 64;
        int nact = __popcll(am);
        if (next > nact) next = nact;
        atomicAdd(&cnt[b], next - lane);
    }
}

// hierarchical scan: bsum -> bscan (1 block) -> rowptr
__global__ void k_bsum(const int* __restrict__ deg, int N, int* __restrict__ bsum) {
    __shared__ int sh[256];
    int t = threadIdx.x, i = blockIdx.x * 256 + t;
    sh[t] = (i < N) ? deg[i] : 0;
    __syncthreads();
    for (int o = 128; o > 0; o >>= 1) {
        if (t < o) sh[t] += sh[t + o];
        __syncthreads();
    }
    if (t == 0) bsum[blockIdx.x] = sh[0];
}

__global__ void k_bscan(const int* __restrict__ bsum, int P, int* __restrict__ boff,
                        int* __restrict__ rowptr, int N) {
    __shared__ int sh[256];
    int t = threadIdx.x;
    int v = (t < P) ? bsum[t] : 0;
    sh[t] = v;
    __syncthreads();
    for (int o = 1; o < 256; o <<= 1) {
        int u = (t >= o) ? sh[t - o] : 0;
        __syncthreads();
        sh[t] += u;
        __syncthreads();
    }
    if (t < P) boff[t] = sh[t] - v;
    if (t == 255) rowptr[N] = sh[255];
}

__global__ void k_rowptr(const int* __restrict__ deg, const int* __restrict__ boff, int N,
                         int* __restrict__ rowptr) {
    __shared__ int sh[256];
    int t = threadIdx.x, i = blockIdx.x * 256 + t;
    int v = (i < N) ? deg[i] : 0;
    sh[t] = v;
    __syncthreads();
    for (int o = 1; o < 256; o <<= 1) {
        int u = (t >= o) ? sh[t - o] : 0;
        __syncthreads();
        sh[t] += u;
        __syncthreads();
    }
    int ex = sh[t] - v + boff[blockIdx.x];
    if (i < N) rowptr[i] = ex;
}

__global__ void k_scatter2(const int* __restrict__ ei, const int* __restrict__ rank,
                           const int* __restrict__ rowptr, int E, int* __restrict__ csr_eid) {
    int e = blockIdx.x * blockDim.x + threadIdx.x;
    if (e >= E) return;
    int r = rank[e];
    if (r >= 0) {
        int d = ei[E + e];
        csr_eid[rowptr[d] + r] = e;
    }
}

// gather-permute: coalesced writes of csr_src + eaPerm(f16, [edge][16])
__global__ void k_permute(const int* __restrict__ csr_eid, const int* __restrict__ ei,
                          const float* __restrict__ edge_attr, const int* __restrict__ EnPtr,
                          int* __restrict__ csr_src, __half* __restrict__ eaPerm, int E) {
    int En = EnPtr[0];
    int j = blockIdx.x * blockDim.x + threadIdx.x;
    if (j >= En) return;
    int eid = csr_eid[j];
    csr_src[j] = ei[eid];
    const float4* ea4 = (const float4*)(edge_attr + (size_t)eid * 16);
    float4 a = ea4[0], b = ea4[1], c = ea4[2], dd = ea4[3];
    union { __half h[8]; float4 f; } u0, u1;
    u0.h[0] = __float2half(a.x); u0.h[1] = __float2half(a.y);
    u0.h[2] = __float2half(a.z); u0.h[3] = __float2half(a.w);
    u0.h[4] = __float2half(b.x); u0.h[5] = __float2half(b.y);
    u0.h[6] = __float2half(b.z); u0.h[7] = __float2half(b.w);
    u1.h[0] = __float2half(c.x); u1.h[1] = __float2half(c.y);
    u1.h[2] = __float2half(c.z); u1.h[3] = __float2half(c.w);
    u1.h[4] = __float2half(dd.x); u1.h[5] = __float2half(dd.y);
    u1.h[6] = __float2half(dd.z); u1.h[7] = __float2half(dd.w);
    float4* out = (float4*)(eaPerm + (size_t)j * 16);
    out[0] = u0.f; out[1] = u1.f;
}

// 4x4 micro-tile GEMM; AT transposed in LDS (given stride), W row-major in LDS.
template <int STRIDE>
__device__ __forceinline__ void gemm_tile(const float* AT, const float* W, float acc[4][4], int ty, int tx) {
    #pragma unroll
    for (int i = 0; i < 4; i++)
        #pragma unroll
        for (int j = 0; j < 4; j++) acc[i][j] = 0.f;
    #pragma unroll 4
    for (int k = 0; k < 64; k++) {
        const float4 a4 = *(const float4*)(AT + k * STRIDE + ty * 4);
        const float4 b4 = *(const float4*)(W + k * 64 + tx * 4);
        float a[4] = {a4.x, a4.y, a4.z, a4.w};
        float b[4] = {b4.x, b4.y, b4.z, b4.w};
        #pragma unroll
        for (int i = 0; i < 4; i++)
            #pragma unroll
            for (int j = 0; j < 4; j++) acc[i][j] += a[i] * b[j];
    }
}

// packed xW1 index: channel c -> p = (c&15)*4 + (c>>4)  (4 tiles of col n contiguous)
__device__ __forceinline__ int xw1_pack(int c) { return ((c & 15) << 2) | (c >> 4); }

// Standalone prep kernel:
//  blocks 0..4  : P[l], pb[l];  5..8: Q[l], qb[l];  9..12: R[l], rb[l]
//  blocks 13..17: Bfrag[l] (mfma B-operand fragments of We, K zero-padded to 32)
//  blocks 18..  : layer-0 node GEMMs: xW1p(f16 packed) = x@Wx0, xA0(f32) = x@A0
__global__ void k_prep(const float* __restrict__ X,
                       const float* nn2_w1, const float* nn2_w2, const float* nn2_b2,
                       const float* nn1_w1, const float* nn1_w2, const float* nn1_b2,
                       float* P, float* pb, float* Q, float* qb, float* R, float* rb,
                       __half* Bfrag, __half* __restrict__ xW1p, float* __restrict__ xA0,
                       int N) {
    __shared__ float XT[64 * 68];
    __shared__ float W[64 * 64];
    int job = blockIdx.x;
    int t = threadIdx.x;
    if (job >= 13 && job < 18) {
        int l = job - 13;
        const float* We = nn2_w1 + (size_t)l * 5120 + 64 * 64;  // [16][64]
        for (int idx = t; idx < 2048; idx += 256) {
            int tt = idx >> 9;          // tile 0..3
            int lane = (idx >> 3) & 63;
            int j = idx & 7;
            int k = (lane >> 4) * 8 + j;
            int n = lane & 15;
            float v = (k < 16) ? We[k * 64 + tt * 16 + n] : 0.f;
            Bfrag[((size_t)(l * 4 + tt) * 64 + lane) * 8 + j] = __float2half(v);
        }
        return;
    }
    if (job < 13) {
        const float* left; const float* lb; const float* right; float* out; float* ob;
        if (job < 5) {
            int l = job;
            left = nn2_w2 + l * 4096; lb = nn2_b2 + l * 64; right = nn1_w1 + l * 4096;
            out = P + l * 4096; ob = pb + l * 64;
        } else if (job < 9) {
            int l = job - 5;
            left = nn1_w2 + l * 4096; lb = nn1_b2 + l * 64; right = nn2_w1 + (l + 1) * 5120;
            out = Q + l * 4096; ob = qb + l * 64;
        } else {
            int l = job - 9;
            left = nn1_w2 + l * 4096; lb = nn1_b2 + l * 64; right = nn1_w1 + (l + 1) * 4096;
            out = R + l * 4096; ob = rb + l * 64;
        }
        int r0 = (t >> 4) * 4, c0 = (t & 15) * 4;
        float acc[4][4] = {};
        for (int k = 0; k < 64; k++) {
            float b[4];
            #pragma unroll
            for (int j = 0; j < 4; j++) b[j] = right[k * 64 + c0 + j];
            #pragma unroll
            for (int i = 0; i < 4; i++) {
                float a = left[(r0 + i) * 64 + k];
                #pragma unroll
                for (int j = 0; j < 4; j++) acc[i][j] += a * b[j];
            }
        }
        for (int i = 0; i < 4; i++)
            for (int j = 0; j < 4; j++)
                out[(r0 + i) * 64 + c0 + j] = acc[i][j];
        if (t < 64) {
            float s = 0.f;
            for (int k = 0; k < 64; k++) s += lb[k] * right[k * 64 + t];
            ob[t] = s;
        }
        return;
    }
    // layer-0 node GEMMs
    int ty = t >> 4, tx = t & 15;
    int base = (job - 18) * 64;
    for (int q = 0; q < 4; q++) {
        int row = ty + q * 16;
        int gr = base + row;
        float4 v = make_float4(0.f, 0.f, 0.f, 0.f);
        if (gr < N) v = *(const float4*)(X + (size_t)gr * 64 + tx * 4);
        XT[(tx * 4 + 0) * 68 + row] = v.x;
        XT[(tx * 4 + 1) * 68 + row] = v.y;
        XT[(tx * 4 + 2) * 68 + row] = v.z;
        XT[(tx * 4 + 3) * 68 + row] = v.w;
    }
    for (int q = 0; q < 4; q++) ((float4*)W)[t + q * 256] = ((const float4*)nn2_w1)[t + q * 256];
    __syncthreads();
    float acc[4][4];
    gemm_tile<68>(XT, W, acc, ty, tx);
    for (int i = 0; i < 4; i++) {
        int gr = base + ty * 4 + i;
        if (gr < N) {
            #pragma unroll
            for (int j = 0; j < 4; j++) {
                int c = tx * 4 + j;
                xW1p[(size_t)gr * 64 + xw1_pack(c)] = __float2half(acc[i][j]);
            }
        }
    }
    __syncthreads();
    for (int q = 0; q < 4; q++) ((float4*)W)[t + q * 256] = ((const float4*)nn1_w1)[t + q * 256];
    __syncthreads();
    gemm_tile<68>(XT, W, acc, ty, tx);
    for (int i = 0; i < 4; i++) {
        int gr = base + ty * 4 + i;
        if (gr < N) {
            float4 o = make_float4(acc[i][0], acc[i][1], acc[i][2], acc[i][3]);
            *(float4*)(xA0 + (size_t)gr * 64 + tx * 4) = o;
        }
    }
}

// Edge phase (MFMA): one wave per destination node. Per 16-edge chunk:
//   S[16 edges][64 ch] = EA[16][16] @ We[16][64] via 4x mfma_f32_16x16x32_f16
//   (K zero-padded 16->32; b1 folded into C). Lane holds col n=lane&15,
//   rows quad*4+reg -> epilogue adds gathered xW1p, ReLU, accumulates.
__global__ __launch_bounds__(256, 4) void k_edge(
        const int* __restrict__ rowptr, const int* __restrict__ csr_src,
        const __half* __restrict__ eaPerm, const __half* __restrict__ xW1p,
        const __half* __restrict__ Bfrag, const float* __restrict__ b1m,
        float* __restrict__ Hsum, int N) {
    int t = threadIdx.x;
    int wave = t >> 6, lane = t & 63;
    int wid = __builtin_amdgcn_readfirstlane(blockIdx.x * 4 + wave);
    if (wid >= N) return;
    int quad = lane >> 4, n = lane & 15;
    f16x8 Bf[4];
    f32x4v Cini[4];
    #pragma unroll
    for (int tt = 0; tt < 4; tt++) {
        Bf[tt] = *(const f16x8*)(Bfrag + ((size_t)tt * 64 + lane) * 8);
        float b = b1m[tt * 16 + n];
        Cini[tt][0] = b; Cini[tt][1] = b; Cini[tt][2] = b; Cini[tt][3] = b;
    }
    int beg = __builtin_amdgcn_readfirstlane(rowptr[wid]);
    int end = __builtin_amdgcn_readfirstlane(rowptr[wid + 1]);
    float acc[4] = {0.f, 0.f, 0.f, 0.f};
    for (int cbeg = beg; cbeg < end; cbeg += 16) {
        int m = end - cbeg; m = (m < 16) ? m : 16;
        // stage srcs (lanes 0-15, coalesced)
        int srcv = 0;
        if (lane < 16) {
            int ii = (lane < m) ? lane : (m - 1);
            srcv = __builtin_nontemporal_load(csr_src + cbeg + ii);
        }
        // A fragment: lanes 0-31 read 16B of eaPerm (edge=n, k-half=quad); zero pad
        f16x8 Af;
        #pragma unroll
        for (int j = 0; j < 8; j++) Af[j] = (_Float16)0;
        if (quad < 2) {
            const f16x8* ap = (const f16x8*)((const char*)eaPerm + ((size_t)(cbeg + n) << 5) + ((size_t)quad << 4));
            f16x8 av = *ap;
            if (n < m) Af = av;
        }
        // xv gathers: lane loads 8B (4 tiles of col n) for edge quad*4+r
        uint2 xv[4];
        #pragma unroll
        for (int r = 0; r < 4; r++) {
            int e = quad * 4 + r;
            int s = __shfl(srcv, e);
            xv[r] = *(const uint2*)(xW1p + (size_t)s * 64 + n * 4);
        }
        // matrix multiply: D[tt] = EA@We_tile + b1
        f32x4v D[4];
        #pragma unroll
        for (int tt = 0; tt < 4; tt++)
            D[tt] = __builtin_amdgcn_mfma_f32_16x16x32_f16(Af, Bf[tt], Cini[tt], 0, 0, 0);
        if (m == 16) {
            #pragma unroll
            for (int r = 0; r < 4; r++) {
                f16x4 xh = __builtin_bit_cast(f16x4, xv[r]);
                #pragma unroll
                for (int tt = 0; tt < 4; tt++) {
                    float z = D[tt][r] + (float)xh[tt];
                    acc[tt] += fmaxf(z, 0.f);
                }
            }
        } else {
            #pragma unroll
            for (int r = 0; r < 4; r++) {
                int e = quad * 4 + r;
                f16x4 xh = __builtin_bit_cast(f16x4, xv[r]);
                #pragma unroll
                for (int tt = 0; tt < 4; tt++) {
                    float z = fmaxf(D[tt][r] + (float)xh[tt], 0.f);
                    acc[tt] += (e < m) ? z : 0.f;
                }
            }
        }
    }
    #pragma unroll
    for (int tt = 0; tt < 4; tt++) {
        acc[tt] += __shfl_xor(acc[tt], 16);
        acc[tt] += __shfl_xor(acc[tt], 32);
    }
    if (quad == 0) {
        #pragma unroll
        for (int tt = 0; tt < 4; tt++)
            Hsum[(size_t)wid * 64 + tt * 16 + n] = acc[tt];
    }
}

// Node phase for layer l (64-node tiles, AT reused for HT).
// Pooled readout LDS-pre-reduced. out1 written in packed-f16 layout for k_edge.
__global__ void k_node(const float* __restrict__ Hsum, const float* __restrict__ xA,
                       const int* __restrict__ deg, const int* __restrict__ batch,
                       const float* __restrict__ P, const float* __restrict__ pb,
                       const float* __restrict__ a_l, const float* __restrict__ epsp,
                       const float* __restrict__ Q, const float* __restrict__ qb,
                       __half* __restrict__ out1,
                       const float* __restrict__ R, const float* __restrict__ rb,
                       float* __restrict__ out2,
                       float* __restrict__ hpool_l, int N, int has_next) {
    __shared__ float AT[64 * 68];   // Hsum^T, later reused as HT
    __shared__ float W[64 * 64];
    __shared__ float shp[8 * 64];
    int t = threadIdx.x, ty = t >> 4, tx = t & 15;
    int base = blockIdx.x * 64;
    int lastn = base + 63; if (lastn > N - 1) lastn = N - 1;
    int gmin = batch[base];
    int span = batch[lastn] - gmin + 1;
    if (span <= 8) {
        for (int q = t; q < span * 64; q += 256) shp[q] = 0.f;
    }
    for (int q = 0; q < 4; q++) {
        int row = ty + q * 16;
        int gr = base + row;
        float4 v = make_float4(0.f, 0.f, 0.f, 0.f);
        if (gr < N) v = *(const float4*)(Hsum + (size_t)gr * 64 + tx * 4);
        AT[(tx * 4 + 0) * 68 + row] = v.x;
        AT[(tx * 4 + 1) * 68 + row] = v.y;
        AT[(tx * 4 + 2) * 68 + row] = v.z;
        AT[(tx * 4 + 3) * 68 + row] = v.w;
    }
    for (int q = 0; q < 4; q++) ((float4*)W)[t + q * 256] = ((const float4*)P)[t + q * 256];
    __syncthreads();
    float acc[4][4];
    gemm_tile<68>(AT, W, acc, ty, tx);
    float eps1 = 1.f + epsp[0];
    float4 pbv = *(const float4*)(pb + tx * 4);
    float4 av = *(const float4*)(a_l + tx * 4);
    float h[4][4];
    int gidx[4];
    for (int i = 0; i < 4; i++) {
        int gr = base + ty * 4 + i;
        float dg = 0.f;
        float4 xa = make_float4(0.f, 0.f, 0.f, 0.f);
        if (gr < N) {
            dg = (float)deg[gr];
            xa = *(const float4*)(xA + (size_t)gr * 64 + tx * 4);
            gidx[i] = batch[gr];
        } else {
            gidx[i] = -1;
        }
        h[i][0] = fmaxf(acc[i][0] + eps1 * xa.x + dg * pbv.x + av.x, 0.f);
        h[i][1] = fmaxf(acc[i][1] + eps1 * xa.y + dg * pbv.y + av.y, 0.f);
        h[i][2] = fmaxf(acc[i][2] + eps1 * xa.z + dg * pbv.z + av.z, 0.f);
        h[i][3] = fmaxf(acc[i][3] + eps1 * xa.w + dg * pbv.w + av.w, 0.f);
    }
    if (span <= 8) {
        #pragma unroll
        for (int j = 0; j < 4; j++) {
            int i = 0;
            while (i < 4) {
                if (gidx[i] < 0) { i++; continue; }
                int g = gidx[i];
                float s = h[i][j];
                int k2 = i + 1;
                while (k2 < 4 && gidx[k2] == g) { s += h[k2][j]; k2++; }
                atomicAdd(&shp[(g - gmin) * 64 + tx * 4 + j], s);
                i = k2;
            }
        }
        __syncthreads();
        for (int q = t; q < span * 64; q += 256) {
            float v = shp[q];
            if (v != 0.f) atomicAdd(&hpool_l[(gmin + (q >> 6)) * 64 + (q & 63)], v);
        }
    } else {
        #pragma unroll
        for (int j = 0; j < 4; j++) {
            int i = 0;
            while (i < 4) {
                if (gidx[i] < 0) { i++; continue; }
                int g = gidx[i];
                float s = h[i][j];
                int k2 = i + 1;
                while (k2 < 4 && gidx[k2] == g) { s += h[k2][j]; k2++; }
                atomicAdd(&hpool_l[g * 64 + tx * 4 + j], s);
                i = k2;
            }
        }
    }
    if (has_next) {
        __syncthreads();
        for (int i = 0; i < 4; i++)
            for (int j = 0; j < 4; j++)
                AT[(tx * 4 + j) * 68 + ty * 4 + i] = h[i][j];
        for (int q = 0; q < 4; q++) ((float4*)W)[t + q * 256] = ((const float4*)Q)[t + q * 256];
        __syncthreads();
        gemm_tile<68>(AT, W, acc, ty, tx);
        float4 qbv = *(const float4*)(qb + tx * 4);
        for (int i = 0; i < 4; i++) {
            int gr = base + ty * 4 + i;
            if (gr < N) {
                float vals[4] = {acc[i][0] + qbv.x, acc[i][1] + qbv.y,
                                 acc[i][2] + qbv.z, acc[i][3] + qbv.w};
                #pragma unroll
                for (int j = 0; j < 4; j++) {
                    int c = tx * 4 + j;
                    out1[(size_t)gr * 64 + xw1_pack(c)] = __float2half(vals[j]);
                }
            }
        }
        __syncthreads();
        for (int q = 0; q < 4; q++) ((float4*)W)[t + q * 256] = ((const float4*)R)[t + q * 256];
        __syncthreads();
        gemm_tile<68>(AT, W, acc, ty, tx);
        float4 rbv = *(const float4*)(rb + tx * 4);
        for (int i = 0; i < 4; i++) {
            int gr = base + ty * 4 + i;
            if (gr < N) {
                float4 o = make_float4(acc[i][0] + rbv.x, acc[i][1] + rbv.y,
                                       acc[i][2] + rbv.z, acc[i][3] + rbv.w);
                *(float4*)(out2 + (size_t)gr * 64 + tx * 4) = o;
            }
        }
    }
}

// fused readout: feats then final MLP
__global__ void k_pool_final(const float* __restrict__ hpool, const int* __restrict__ cnt,
                             const float* __restrict__ nn1_w2, const float* __restrict__ nn1_b2,
                             const float* __restrict__ F1, const float* __restrict__ fb1,
                             const float* __restrict__ F2, const float* __restrict__ fb2,
                             float* __restrict__ out, int G) {
    int g = blockIdx.x;
    int c = threadIdx.x; // 320
    int l = c >> 6, cc = c & 63;
    const float* hp = hpool + ((size_t)l * G + g) * 64;
    const float* B = nn1_w2 + l * 4096;
    float s = (float)cnt[g] * nn1_b2[l * 64 + cc];
    for (int k = 0; k < 64; k++) s += hp[k] * B[k * 64 + cc];
    __shared__ float sh1[320];
    __shared__ float sh2[320];
    sh1[c] = s;
    __syncthreads();
    float t2 = fb1[c];
    for (int k = 0; k < 320; k++) t2 += sh1[k] * F1[k * 320 + c];
    t2 = fmaxf(t2, 0.f);
    sh2[c] = t2 * F2[c];
    __syncthreads();
    if (c == 0) {
        float y = fb2[0];
        for (int k = 0; k < 320; k++) y += sh2[k];
        out[g] = y;
    }
}

extern "C" void kernel_launch(void* const* d_in, const int* in_sizes, int n_in,
                              void* d_out, int out_size, void* d_ws, size_t ws_size,
                              hipStream_t stream) {
    const float* x        = (const float*)d_in[0];
    const int*   ei       = (const int*)d_in[1];
    const float* edge_attr= (const float*)d_in[2];
    const int*   batch    = (const int*)d_in[3];
    const float* nn2_w1   = (const float*)d_in[4];
    const float* nn2_b1   = (const float*)d_in[5];
    const float* nn2_w2   = (const float*)d_in[6];
    const float* nn2_b2   = (const float*)d_in[7];
    const float* nn1_w1   = (const float*)d_in[8];
    const float* nn1_b1   = (const float*)d_in[9];
    const float* nn1_w2   = (const float*)d_in[10];
    const float* nn1_b2   = (const float*)d_in[11];
    const float* fin_w1   = (const float*)d_in[12];
    const float* fin_b1   = (const float*)d_in[13];
    const float* fin_w2   = (const float*)d_in[14];
    const float* fin_b2   = (const float*)d_in[15];
    const float* eps      = (const float*)d_in[16];

    int N = in_sizes[0] / 64;
    int E = in_sizes[1] / 2;
    int G = out_size;

    char* p = (char*)d_ws;
    auto alloc = [&](size_t bytes) -> char* {
        char* r = p;
        p += (bytes + 255) & ~(size_t)255;
        return r;
    };
    int*    deg     = (int*)alloc((size_t)N * 4);
    int*    cnt     = (int*)alloc((size_t)G * 4);
    int*    rowptr  = (int*)alloc((size_t)(N + 1) * 4);
    int*    rank    = (int*)alloc((size_t)E * 4);
    int*    bsum    = (int*)alloc(256 * 4);
    int*    boff    = (int*)alloc(256 * 4);
    int*    csr_eid = (int*)alloc((size_t)E * 4);
    int*    csr_src = (int*)alloc((size_t)E * 4 + 256);
    __half* eaPerm  = (__half*)alloc((size_t)E * 16 * 2 + 1024);
    __half* xW1p    = (__half*)alloc((size_t)N * 64 * 2);
    float*  xA0     = (float*)alloc((size_t)N * 64 * 4);
    float*  xA1     = (float*)alloc((size_t)N * 64 * 4);
    float*  Hsum    = (float*)alloc((size_t)N * 64 * 4);
    float*  hpool   = (float*)alloc((size_t)NLAYERS * G * 64 * 4);
    float*  P       = (float*)alloc(5 * 4096 * 4);
    float*  pb      = (float*)alloc(5 * 64 * 4);
    float*  Q       = (float*)alloc(4 * 4096 * 4);
    float*  qb      = (float*)alloc(4 * 64 * 4);
    float*  R       = (float*)alloc(4 * 4096 * 4);
    float*  rb      = (float*)alloc(4 * 64 * 4);
    __half* Bfrag   = (__half*)alloc(5 * 4 * 64 * 8 * 2);

    hipMemsetAsync(deg, 0, (size_t)N * 4, stream);
    hipMemsetAsync(cnt, 0, (size_t)G * 4, stream);
    hipMemsetAsync(hpool, 0, (size_t)NLAYERS * G * 64 * 4, stream);

    int Pblk = (N + 255) / 256;
    int nb64 = (N + 63) / 64;
    int EB = (E + 255) / 256;
    k_rank<<<EB, 256, 0, stream>>>(ei, E, deg, rank, batch, N, cnt);
    k_prep<<<18 + nb64, 256, 0, stream>>>(x, nn2_w1, nn2_w2, nn2_b2, nn1_w1, nn1_w2, nn1_b2,
                                          P, pb, Q, qb, R, rb, Bfrag, xW1p, xA0, N);
    k_bsum<<<Pblk, 256, 0, stream>>>(deg, N, bsum);
    k_bscan<<<1, 256, 0, stream>>>(bsum, Pblk, boff, rowptr, N);
    k_rowptr<<<Pblk, 256, 0, stream>>>(deg, boff, N, rowptr);
    k_scatter2<<<EB, 256, 0, stream>>>(ei, rank, rowptr, E, csr_eid);
    k_permute<<<EB, 256, 0, stream>>>(csr_eid, ei, edge_attr, rowptr + N, csr_src, eaPerm, E);

    float* xA_cur = xA0;
    float* xA_nxt = xA1;
    int eblocks = (N + 3) / 4; // 4 waves/block, one wave per node
    for (int l = 0; l < NLAYERS; l++) {
        int has_next = (l < NLAYERS - 1) ? 1 : 0;
        k_edge<<<eblocks, 256, 0, stream>>>(rowptr, csr_src, eaPerm, xW1p,
                                            Bfrag + (size_t)l * 2048, nn2_b1 + l * 64, Hsum, N);
        k_node<<<nb64, 256, 0, stream>>>(Hsum, xA_cur, deg, batch,
                                         P + l * 4096, pb + l * 64, nn1_b1 + l * 64, eps,
                                         Q + (has_next ? l : 0) * 4096, qb + (has_next ? l : 0) * 64, xW1p,
                                         R + (has_next ? l : 0) * 4096, rb + (has_next ? l : 0) * 64, xA_nxt,
                                         hpool + (size_t)l * G * 64, N, has_next);
        float* tmp = xA_cur; xA_cur = xA_nxt; xA_nxt = tmp;
    }

    k_pool_final<<<G, 320, 0, stream>>>(hpool, cnt, nn1_w2, nn1_b2,
                                        fin_w1, fin_b1, fin_w2, fin_b2, (float*)d_out, G);
}

// Round 12
// 507.749 us; speedup vs baseline: 1.2141x; 1.1498x over previous
//
#include <hip/hip_runtime.h>
#include <hip/hip_fp16.h>

#define NLAYERS 5

struct alignas(8) H4 { __half h[4]; };

typedef _Float16 f16x8 __attribute__((ext_vector_type(8)));
typedef _Float16 f16x4 __attribute__((ext_vector_type(4)));
typedef float f32x4v __attribute__((ext_vector_type(4)));

// ---------------- setup kernels ----------------
// one thread per edge: deg histogram + rank. cnt histogram wave-aggregated.
__global__ void k_rank(const int* __restrict__ ei, int E, int* __restrict__ deg,
                       int* __restrict__ rank, const int* __restrict__ batch, int N,
                       int* __restrict__ cnt) {
    int t = threadIdx.x;
    int i = blockIdx.x * 256 + t;
    int lane = t & 63;
    if (i < E) {
        int s = ei[i], d = ei[E + i];
        rank[i] = (s != d) ? atomicAdd(&deg[d], 1) : -1;
    }
    bool valid = (i < N);
    int b = valid ? batch[i] : -1;
    int prevb = __shfl_up(b, 1);
    bool leader = valid && ((lane == 0) || (prevb != b));
    unsigned long long lm = __ballot(leader);
    unsigned long long am = __ballot(valid);
    if (leader) {
        unsigned long long above = (lane < 63) ? (lm >> (lane + 1)) : 0ULL;
        int next = above ? (lane + 1 + (__ffsll((long long)above) - 1)) : 64;
        int nact = __popcll(am);
        if (next > nact) next = nact;
        atomicAdd(&cnt[b], next - lane);
    }
}

// hierarchical scan: bsum -> bscan (1 block) -> rowptr
__global__ void k_bsum(const int* __restrict__ deg, int N, int* __restrict__ bsum) {
    __shared__ int sh[256];
    int t = threadIdx.x, i = blockIdx.x * 256 + t;
    sh[t] = (i < N) ? deg[i] : 0;
    __syncthreads();
    for (int o = 128; o > 0; o >>= 1) {
        if (t < o) sh[t] += sh[t + o];
        __syncthreads();
    }
    if (t == 0) bsum[blockIdx.x] = sh[0];
}

__global__ void k_bscan(const int* __restrict__ bsum, int P, int* __restrict__ boff,
                        int* __restrict__ rowptr, int N) {
    __shared__ int sh[256];
    int t = threadIdx.x;
    int v = (t < P) ? bsum[t] : 0;
    sh[t] = v;
    __syncthreads();
    for (int o = 1; o < 256; o <<= 1) {
        int u = (t >= o) ? sh[t - o] : 0;
        __syncthreads();
        sh[t] += u;
        __syncthreads();
    }
    if (t < P) boff[t] = sh[t] - v;
    if (t == 255) rowptr[N] = sh[255];
}

__global__ void k_rowptr(const int* __restrict__ deg, const int* __restrict__ boff, int N,
                         int* __restrict__ rowptr) {
    __shared__ int sh[256];
    int t = threadIdx.x, i = blockIdx.x * 256 + t;
    int v = (i < N) ? deg[i] : 0;
    sh[t] = v;
    __syncthreads();
    for (int o = 1; o < 256; o <<= 1) {
        int u = (t >= o) ? sh[t - o] : 0;
        __syncthreads();
        sh[t] += u;
        __syncthreads();
    }
    int ex = sh[t] - v + boff[blockIdx.x];
    if (i < N) rowptr[i] = ex;
}

__global__ void k_scatter2(const int* __restrict__ ei, const int* __restrict__ rank,
                           const int* __restrict__ rowptr, int E, int* __restrict__ csr_eid) {
    int e = blockIdx.x * blockDim.x + threadIdx.x;
    if (e >= E) return;
    int r = rank[e];
    if (r >= 0) {
        int d = ei[E + e];
        csr_eid[rowptr[d] + r] = e;
    }
}

// gather-permute: coalesced writes of csr_src + eaPerm(f16, [edge][16])
__global__ void k_permute(const int* __restrict__ csr_eid, const int* __restrict__ ei,
                          const float* __restrict__ edge_attr, const int* __restrict__ EnPtr,
                          int* __restrict__ csr_src, __half* __restrict__ eaPerm, int E) {
    int En = EnPtr[0];
    int j = blockIdx.x * blockDim.x + threadIdx.x;
    if (j >= En) return;
    int eid = csr_eid[j];
    csr_src[j] = ei[eid];
    const float4* ea4 = (const float4*)(edge_attr + (size_t)eid * 16);
    float4 a = ea4[0], b = ea4[1], c = ea4[2], dd = ea4[3];
    union { __half h[8]; float4 f; } u0, u1;
    u0.h[0] = __float2half(a.x); u0.h[1] = __float2half(a.y);
    u0.h[2] = __float2half(a.z); u0.h[3] = __float2half(a.w);
    u0.h[4] = __float2half(b.x); u0.h[5] = __float2half(b.y);
    u0.h[6] = __float2half(b.z); u0.h[7] = __float2half(b.w);
    u1.h[0] = __float2half(c.x); u1.h[1] = __float2half(c.y);
    u1.h[2] = __float2half(c.z); u1.h[3] = __float2half(c.w);
    u1.h[4] = __float2half(dd.x); u1.h[5] = __float2half(dd.y);
    u1.h[6] = __float2half(dd.z); u1.h[7] = __float2half(dd.w);
    float4* out = (float4*)(eaPerm + (size_t)j * 16);
    out[0] = u0.f; out[1] = u1.f;
}

// 4x4 micro-tile GEMM; AT transposed in LDS (given stride), W row-major in LDS.
template <int STRIDE>
__device__ __forceinline__ void gemm_tile(const float* AT, const float* W, float acc[4][4], int ty, int tx) {
    #pragma unroll
    for (int i = 0; i < 4; i++)
        #pragma unroll
        for (int j = 0; j < 4; j++) acc[i][j] = 0.f;
    #pragma unroll 4
    for (int k = 0; k < 64; k++) {
        const float4 a4 = *(const float4*)(AT + k * STRIDE + ty * 4);
        const float4 b4 = *(const float4*)(W + k * 64 + tx * 4);
        float a[4] = {a4.x, a4.y, a4.z, a4.w};
        float b[4] = {b4.x, b4.y, b4.z, b4.w};
        #pragma unroll
        for (int i = 0; i < 4; i++)
            #pragma unroll
            for (int j = 0; j < 4; j++) acc[i][j] += a[i] * b[j];
    }
}

// packed xW1 index: channel c -> p = (c&15)*4 + (c>>4)
__device__ __forceinline__ int xw1_pack(int c) { return ((c & 15) << 2) | (c >> 4); }

// Standalone prep kernel:
//  blocks 0..4  : Pf[l] f16 B-fragments + pb[l];  5..8: Qf[l]+qb;  9..12: Rf[l]+rb
//  blocks 13..17: Bfrag[l] (We fragments, K zero-padded to 32)
//  blocks 18..  : layer-0 node GEMMs: xW1p(f16 packed) = x@Wx0, xA0(f32) = x@A0
// B-fragment convention (R11-verified): element (k,c) -> Ff[((nt*2+kh)*64 + q*16+nn)*8 + jj]
//   nt=c>>4, nn=c&15, kh=k>>5, q=(k&31)>>3, jj=k&7
__global__ void k_prep(const float* __restrict__ X,
                       const float* nn2_w1, const float* nn2_w2, const float* nn2_b2,
                       const float* nn1_w1, const float* nn1_w2, const float* nn1_b2,
                       __half* Ff, float* pb, float* qb, float* rb,
                       __half* Bfrag, __half* __restrict__ xW1p, float* __restrict__ xA0,
                       int N) {
    __shared__ float XT[64 * 68];
    __shared__ float W[64 * 64];
    int job = blockIdx.x;
    int t = threadIdx.x;
    if (job >= 13 && job < 18) {
        int l = job - 13;
        const float* We = nn2_w1 + (size_t)l * 5120 + 64 * 64;  // [16][64]
        for (int idx = t; idx < 2048; idx += 256) {
            int tt = idx >> 9;
            int lane = (idx >> 3) & 63;
            int j = idx & 7;
            int k = (lane >> 4) * 8 + j;
            int n = lane & 15;
            float v = (k < 16) ? We[k * 64 + tt * 16 + n] : 0.f;
            Bfrag[((size_t)(l * 4 + tt) * 64 + lane) * 8 + j] = __float2half(v);
        }
        return;
    }
    if (job < 13) {
        const float* left; const float* lb; const float* right; float* ob;
        if (job < 5) {
            int l = job;
            left = nn2_w2 + l * 4096; lb = nn2_b2 + l * 64; right = nn1_w1 + l * 4096;
            ob = pb + l * 64;
        } else if (job < 9) {
            int l = job - 5;
            left = nn1_w2 + l * 4096; lb = nn1_b2 + l * 64; right = nn2_w1 + (l + 1) * 5120;
            ob = qb + l * 64;
        } else {
            int l = job - 9;
            left = nn1_w2 + l * 4096; lb = nn1_b2 + l * 64; right = nn1_w1 + (l + 1) * 4096;
            ob = rb + l * 64;
        }
        __half* out = Ff + (size_t)job * 4096;
        int r0 = (t >> 4) * 4, c0 = (t & 15) * 4;
        float acc[4][4] = {};
        for (int k = 0; k < 64; k++) {
            float b[4];
            #pragma unroll
            for (int j = 0; j < 4; j++) b[j] = right[k * 64 + c0 + j];
            #pragma unroll
            for (int i = 0; i < 4; i++) {
                float a = left[(r0 + i) * 64 + k];
                #pragma unroll
                for (int j = 0; j < 4; j++) acc[i][j] += a * b[j];
            }
        }
        // write f16 B-fragments
        for (int i = 0; i < 4; i++) {
            int k = r0 + i;
            int kh = k >> 5, q = (k & 31) >> 3, jj = k & 7;
            for (int j = 0; j < 4; j++) {
                int c = c0 + j;
                int nt = c >> 4, nn = c & 15;
                out[((size_t)(nt * 2 + kh) * 64 + q * 16 + nn) * 8 + jj] = __float2half(acc[i][j]);
            }
        }
        if (t < 64) {
            float s = 0.f;
            for (int k = 0; k < 64; k++) s += lb[k] * right[k * 64 + t];
            ob[t] = s;
        }
        return;
    }
    // layer-0 node GEMMs
    int ty = t >> 4, tx = t & 15;
    int base = (job - 18) * 64;
    for (int q = 0; q < 4; q++) {
        int row = ty + q * 16;
        int gr = base + row;
        float4 v = make_float4(0.f, 0.f, 0.f, 0.f);
        if (gr < N) v = *(const float4*)(X + (size_t)gr * 64 + tx * 4);
        XT[(tx * 4 + 0) * 68 + row] = v.x;
        XT[(tx * 4 + 1) * 68 + row] = v.y;
        XT[(tx * 4 + 2) * 68 + row] = v.z;
        XT[(tx * 4 + 3) * 68 + row] = v.w;
    }
    for (int q = 0; q < 4; q++) ((float4*)W)[t + q * 256] = ((const float4*)nn2_w1)[t + q * 256];
    __syncthreads();
    float acc[4][4];
    gemm_tile<68>(XT, W, acc, ty, tx);
    for (int i = 0; i < 4; i++) {
        int gr = base + ty * 4 + i;
        if (gr < N) {
            #pragma unroll
            for (int j = 0; j < 4; j++) {
                int c = tx * 4 + j;
                xW1p[(size_t)gr * 64 + xw1_pack(c)] = __float2half(acc[i][j]);
            }
        }
    }
    __syncthreads();
    for (int q = 0; q < 4; q++) ((float4*)W)[t + q * 256] = ((const float4*)nn1_w1)[t + q * 256];
    __syncthreads();
    gemm_tile<68>(XT, W, acc, ty, tx);
    for (int i = 0; i < 4; i++) {
        int gr = base + ty * 4 + i;
        if (gr < N) {
            float4 o = make_float4(acc[i][0], acc[i][1], acc[i][2], acc[i][3]);
            *(float4*)(xA0 + (size_t)gr * 64 + tx * 4) = o;
        }
    }
}

// Edge phase (MFMA): one wave per destination node. Hsum written f16 row-major
// (A-fragment-ready for k_node's MFMA GEMM1).
__global__ __launch_bounds__(256, 4) void k_edge(
        const int* __restrict__ rowptr, const int* __restrict__ csr_src,
        const __half* __restrict__ eaPerm, const __half* __restrict__ xW1p,
        const __half* __restrict__ Bfrag, const float* __restrict__ b1m,
        __half* __restrict__ Hsum16, int N) {
    int t = threadIdx.x;
    int wave = t >> 6, lane = t & 63;
    int wid = __builtin_amdgcn_readfirstlane(blockIdx.x * 4 + wave);
    if (wid >= N) return;
    int quad = lane >> 4, n = lane & 15;
    f16x8 Bf[4];
    f32x4v Cini[4];
    #pragma unroll
    for (int tt = 0; tt < 4; tt++) {
        Bf[tt] = *(const f16x8*)(Bfrag + ((size_t)tt * 64 + lane) * 8);
        float b = b1m[tt * 16 + n];
        Cini[tt][0] = b; Cini[tt][1] = b; Cini[tt][2] = b; Cini[tt][3] = b;
    }
    int beg = __builtin_amdgcn_readfirstlane(rowptr[wid]);
    int end = __builtin_amdgcn_readfirstlane(rowptr[wid + 1]);
    float acc[4] = {0.f, 0.f, 0.f, 0.f};
    for (int cbeg = beg; cbeg < end; cbeg += 16) {
        int m = end - cbeg; m = (m < 16) ? m : 16;
        int srcv = 0;
        if (lane < 16) {
            int ii = (lane < m) ? lane : (m - 1);
            srcv = __builtin_nontemporal_load(csr_src + cbeg + ii);
        }
        f16x8 Af;
        #pragma unroll
        for (int j = 0; j < 8; j++) Af[j] = (_Float16)0;
        if (quad < 2) {
            const f16x8* ap = (const f16x8*)((const char*)eaPerm + ((size_t)(cbeg + n) << 5) + ((size_t)quad << 4));
            f16x8 av = *ap;
            if (n < m) Af = av;
        }
        uint2 xv[4];
        #pragma unroll
        for (int r = 0; r < 4; r++) {
            int e = quad * 4 + r;
            int s = __shfl(srcv, e);
            xv[r] = *(const uint2*)(xW1p + (size_t)s * 64 + n * 4);
        }
        f32x4v D[4];
        #pragma unroll
        for (int tt = 0; tt < 4; tt++)
            D[tt] = __builtin_amdgcn_mfma_f32_16x16x32_f16(Af, Bf[tt], Cini[tt], 0, 0, 0);
        if (m == 16) {
            #pragma unroll
            for (int r = 0; r < 4; r++) {
                f16x4 xh = __builtin_bit_cast(f16x4, xv[r]);
                #pragma unroll
                for (int tt = 0; tt < 4; tt++) {
                    float z = D[tt][r] + (float)xh[tt];
                    acc[tt] += fmaxf(z, 0.f);
                }
            }
        } else {
            #pragma unroll
            for (int r = 0; r < 4; r++) {
                int e = quad * 4 + r;
                f16x4 xh = __builtin_bit_cast(f16x4, xv[r]);
                #pragma unroll
                for (int tt = 0; tt < 4; tt++) {
                    float z = fmaxf(D[tt][r] + (float)xh[tt], 0.f);
                    acc[tt] += (e < m) ? z : 0.f;
                }
            }
        }
    }
    #pragma unroll
    for (int tt = 0; tt < 4; tt++) {
        acc[tt] += __shfl_xor(acc[tt], 16);
        acc[tt] += __shfl_xor(acc[tt], 32);
    }
    if (quad == 0) {
        #pragma unroll
        for (int tt = 0; tt < 4; tt++)
            Hsum16[(size_t)wid * 64 + tt * 16 + n] = __float2half(acc[tt]);
    }
}

// Node phase (MFMA): 64 nodes/block, 4 waves, wave handles 16 rows.
//   GEMM1: D = Hsum16 @ Pf (K=64, 2 MFMAs per n-tile)
//   h = ReLU(D + eps1*xA + deg*pb + a_l); pool via LDS; h->LDS f16
//   GEMM2: out1 = h@Qf + qb (packed f16); GEMM3: out2 = h@Rf + rb (f32)
__global__ __launch_bounds__(256) void k_node(
        const __half* __restrict__ Hsum16, const float* __restrict__ xA,
        const int* __restrict__ deg, const int* __restrict__ batch,
        const __half* __restrict__ Pf, const float* __restrict__ pb,
        const float* __restrict__ a_l, const float* __restrict__ epsp,
        const __half* __restrict__ Qf, const float* __restrict__ qb,
        __half* __restrict__ out1,
        const __half* __restrict__ Rf, const float* __restrict__ rb,
        float* __restrict__ out2,
        float* __restrict__ hpool_l, int N, int has_next) {
    __shared__ _Float16 hL[64 * 72];
    __shared__ float shp[8 * 64];
    int t = threadIdx.x;
    int wave = t >> 6, lane = t & 63;
    int quad = lane >> 4, n = lane & 15;
    int base = blockIdx.x * 64;
    int m0 = base + wave * 16;

    int lastn = base + 63; if (lastn > N - 1) lastn = N - 1;
    int gmin = batch[base];
    int span = batch[lastn] - gmin + 1;
    if (span <= 8) {
        for (int q = t; q < span * 64; q += 256) shp[q] = 0.f;
    }

    int arow = m0 + n; if (arow > N - 1) arow = N - 1;
    f16x8 A0 = *(const f16x8*)(Hsum16 + (size_t)arow * 64 + quad * 8);
    f16x8 A1 = *(const f16x8*)(Hsum16 + (size_t)arow * 64 + 32 + quad * 8);

    f32x4v D[4];
    #pragma unroll
    for (int nt = 0; nt < 4; nt++) {
        f16x8 B0 = *(const f16x8*)(Pf + ((size_t)(nt * 2 + 0) * 64 + lane) * 8);
        f16x8 B1 = *(const f16x8*)(Pf + ((size_t)(nt * 2 + 1) * 64 + lane) * 8);
        f32x4v c0 = {0.f, 0.f, 0.f, 0.f};
        c0 = __builtin_amdgcn_mfma_f32_16x16x32_f16(A0, B0, c0, 0, 0, 0);
        D[nt] = __builtin_amdgcn_mfma_f32_16x16x32_f16(A1, B1, c0, 0, 0, 0);
    }

    float eps1 = 1.f + epsp[0];
    float pbv[4], av[4];
    #pragma unroll
    for (int nt = 0; nt < 4; nt++) { pbv[nt] = pb[nt * 16 + n]; av[nt] = a_l[nt * 16 + n]; }

    float h[4][4];   // [r][nt]
    int gidx[4];
    #pragma unroll
    for (int r = 0; r < 4; r++) {
        int node = m0 + quad * 4 + r;
        float dg = 0.f; int g = -1;
        float xa[4] = {0.f, 0.f, 0.f, 0.f};
        if (node < N) {
            dg = (float)deg[node];
            g = batch[node];
            #pragma unroll
            for (int nt = 0; nt < 4; nt++) xa[nt] = xA[(size_t)node * 64 + nt * 16 + n];
        }
        gidx[r] = g;
        #pragma unroll
        for (int nt = 0; nt < 4; nt++)
            h[r][nt] = fmaxf(D[nt][r] + eps1 * xa[nt] + dg * pbv[nt] + av[nt], 0.f);
    }

    if (span <= 8) {
        #pragma unroll
        for (int nt = 0; nt < 4; nt++) {
            int i = 0;
            while (i < 4) {
                if (gidx[i] < 0) { i++; continue; }
                int g = gidx[i];
                float s = h[i][nt];
                int k2 = i + 1;
                while (k2 < 4 && gidx[k2] == g) { s += h[k2][nt]; k2++; }
                atomicAdd(&shp[(g - gmin) * 64 + nt * 16 + n], s);
                i = k2;
            }
        }
        __syncthreads();
        for (int q = t; q < span * 64; q += 256) {
            float v = shp[q];
            if (v != 0.f) atomicAdd(&hpool_l[(gmin + (q >> 6)) * 64 + (q & 63)], v);
        }
    } else {
        #pragma unroll
        for (int nt = 0; nt < 4; nt++) {
            int i = 0;
            while (i < 4) {
                if (gidx[i] < 0) { i++; continue; }
                int g = gidx[i];
                float s = h[i][nt];
                int k2 = i + 1;
                while (k2 < 4 && gidx[k2] == g) { s += h[k2][nt]; k2++; }
                atomicAdd(&hpool_l[g * 64 + nt * 16 + n], s);
                i = k2;
            }
        }
    }

    if (has_next) {
        #pragma unroll
        for (int r = 0; r < 4; r++) {
            int lrow = wave * 16 + quad * 4 + r;
            #pragma unroll
            for (int nt = 0; nt < 4; nt++)
                hL[lrow * 72 + nt * 16 + n] = (_Float16)h[r][nt];
        }
        __syncthreads();
        int lrowA = wave * 16 + n;
        f16x8 hA0 = *(const f16x8*)(hL + lrowA * 72 + quad * 8);
        f16x8 hA1 = *(const f16x8*)(hL + lrowA * 72 + 32 + quad * 8);
        // GEMM2: h@Q -> out1 (packed f16)
        f32x4v D2[4];
        #pragma unroll
        for (int nt = 0; nt < 4; nt++) {
            f16x8 B0 = *(const f16x8*)(Qf + ((size_t)(nt * 2 + 0) * 64 + lane) * 8);
            f16x8 B1 = *(const f16x8*)(Qf + ((size_t)(nt * 2 + 1) * 64 + lane) * 8);
            f32x4v c0 = {0.f, 0.f, 0.f, 0.f};
            c0 = __builtin_amdgcn_mfma_f32_16x16x32_f16(hA0, B0, c0, 0, 0, 0);
            D2[nt] = __builtin_amdgcn_mfma_f32_16x16x32_f16(hA1, B1, c0, 0, 0, 0);
        }
        float qbv[4];
        #pragma unroll
        for (int nt = 0; nt < 4; nt++) qbv[nt] = qb[nt * 16 + n];
        #pragma unroll
        for (int r = 0; r < 4; r++) {
            int node = m0 + quad * 4 + r;
            if (node < N) {
                H4 o;
                #pragma unroll
                for (int nt = 0; nt < 4; nt++) o.h[nt] = __float2half(D2[nt][r] + qbv[nt]);
                *(H4*)(out1 + (size_t)node * 64 + n * 4) = o;  // packed p = n*4+nt
            }
        }
        // GEMM3: h@R -> out2 (f32)
        #pragma unroll
        for (int nt = 0; nt < 4; nt++) {
            f16x8 B0 = *(const f16x8*)(Rf + ((size_t)(nt * 2 + 0) * 64 + lane) * 8);
            f16x8 B1 = *(const f16x8*)(Rf + ((size_t)(nt * 2 + 1) * 64 + lane) * 8);
            f32x4v c0 = {0.f, 0.f, 0.f, 0.f};
            c0 = __builtin_amdgcn_mfma_f32_16x16x32_f16(hA0, B0, c0, 0, 0, 0);
            D2[nt] = __builtin_amdgcn_mfma_f32_16x16x32_f16(hA1, B1, c0, 0, 0, 0);
        }
        float rbv[4];
        #pragma unroll
        for (int nt = 0; nt < 4; nt++) rbv[nt] = rb[nt * 16 + n];
        #pragma unroll
        for (int r = 0; r < 4; r++) {
            int node = m0 + quad * 4 + r;
            if (node < N) {
                #pragma unroll
                for (int nt = 0; nt < 4; nt++)
                    out2[(size_t)node * 64 + nt * 16 + n] = D2[nt][r] + rbv[nt];
            }
        }
    }
}

// fused readout: feats then final MLP
__global__ void k_pool_final(const float* __restrict__ hpool, const int* __restrict__ cnt,
                             const float* __restrict__ nn1_w2, const float* __restrict__ nn1_b2,
                             const float* __restrict__ F1, const float* __restrict__ fb1,
                             const float* __restrict__ F2, const float* __restrict__ fb2,
                             float* __restrict__ out, int G) {
    int g = blockIdx.x;
    int c = threadIdx.x; // 320
    int l = c >> 6, cc = c & 63;
    const float* hp = hpool + ((size_t)l * G + g) * 64;
    const float* B = nn1_w2 + l * 4096;
    float s = (float)cnt[g] * nn1_b2[l * 64 + cc];
    for (int k = 0; k < 64; k++) s += hp[k] * B[k * 64 + cc];
    __shared__ float sh1[320];
    __shared__ float sh2[320];
    sh1[c] = s;
    __syncthreads();
    float t2 = fb1[c];
    for (int k = 0; k < 320; k++) t2 += sh1[k] * F1[k * 320 + c];
    t2 = fmaxf(t2, 0.f);
    sh2[c] = t2 * F2[c];
    __syncthreads();
    if (c == 0) {
        float y = fb2[0];
        for (int k = 0; k < 320; k++) y += sh2[k];
        out[g] = y;
    }
}

extern "C" void kernel_launch(void* const* d_in, const int* in_sizes, int n_in,
                              void* d_out, int out_size, void* d_ws, size_t ws_size,
                              hipStream_t stream) {
    const float* x        = (const float*)d_in[0];
    const int*   ei       = (const int*)d_in[1];
    const float* edge_attr= (const float*)d_in[2];
    const int*   batch    = (const int*)d_in[3];
    const float* nn2_w1   = (const float*)d_in[4];
    const float* nn2_b1   = (const float*)d_in[5];
    const float* nn2_w2   = (const float*)d_in[6];
    const float* nn2_b2   = (const float*)d_in[7];
    const float* nn1_w1   = (const float*)d_in[8];
    const float* nn1_b1   = (const float*)d_in[9];
    const float* nn1_w2   = (const float*)d_in[10];
    const float* nn1_b2   = (const float*)d_in[11];
    const float* fin_w1   = (const float*)d_in[12];
    const float* fin_b1   = (const float*)d_in[13];
    const float* fin_w2   = (const float*)d_in[14];
    const float* fin_b2   = (const float*)d_in[15];
    const float* eps      = (const float*)d_in[16];

    int N = in_sizes[0] / 64;
    int E = in_sizes[1] / 2;
    int G = out_size;

    char* p = (char*)d_ws;
    auto alloc = [&](size_t bytes) -> char* {
        char* r = p;
        p += (bytes + 255) & ~(size_t)255;
        return r;
    };
    int*    deg     = (int*)alloc((size_t)N * 4);
    int*    cnt     = (int*)alloc((size_t)G * 4);
    int*    rowptr  = (int*)alloc((size_t)(N + 1) * 4);
    int*    rank    = (int*)alloc((size_t)E * 4);
    int*    bsum    = (int*)alloc(256 * 4);
    int*    boff    = (int*)alloc(256 * 4);
    int*    csr_eid = (int*)alloc((size_t)E * 4);
    int*    csr_src = (int*)alloc((size_t)E * 4 + 256);
    __half* eaPerm  = (__half*)alloc((size_t)E * 16 * 2 + 1024);
    __half* xW1p    = (__half*)alloc((size_t)N * 64 * 2);
    float*  xA0     = (float*)alloc((size_t)N * 64 * 4);
    float*  xA1     = (float*)alloc((size_t)N * 64 * 4);
    __half* Hsum16  = (__half*)alloc((size_t)N * 64 * 2);
    float*  hpool   = (float*)alloc((size_t)NLAYERS * G * 64 * 4);
    __half* Ff      = (__half*)alloc(13 * 4096 * 2);
    float*  pb      = (float*)alloc(5 * 64 * 4);
    float*  qb      = (float*)alloc(4 * 64 * 4);
    float*  rb      = (float*)alloc(4 * 64 * 4);
    __half* Bfrag   = (__half*)alloc(5 * 4 * 64 * 8 * 2);

    hipMemsetAsync(deg, 0, (size_t)N * 4, stream);
    hipMemsetAsync(cnt, 0, (size_t)G * 4, stream);
    hipMemsetAsync(hpool, 0, (size_t)NLAYERS * G * 64 * 4, stream);

    int Pblk = (N + 255) / 256;
    int nb64 = (N + 63) / 64;
    int EB = (E + 255) / 256;
    k_rank<<<EB, 256, 0, stream>>>(ei, E, deg, rank, batch, N, cnt);
    k_prep<<<18 + nb64, 256, 0, stream>>>(x, nn2_w1, nn2_w2, nn2_b2, nn1_w1, nn1_w2, nn1_b2,
                                          Ff, pb, qb, rb, Bfrag, xW1p, xA0, N);
    k_bsum<<<Pblk, 256, 0, stream>>>(deg, N, bsum);
    k_bscan<<<1, 256, 0, stream>>>(bsum, Pblk, boff, rowptr, N);
    k_rowptr<<<Pblk, 256, 0, stream>>>(deg, boff, N, rowptr);
    k_scatter2<<<EB, 256, 0, stream>>>(ei, rank, rowptr, E, csr_eid);
    k_permute<<<EB, 256, 0, stream>>>(csr_eid, ei, edge_attr, rowptr + N, csr_src, eaPerm, E);

    float* xA_cur = xA0;
    float* xA_nxt = xA1;
    int eblocks = (N + 3) / 4;
    for (int l = 0; l < NLAYERS; l++) {
        int has_next = (l < NLAYERS - 1) ? 1 : 0;
        k_edge<<<eblocks, 256, 0, stream>>>(rowptr, csr_src, eaPerm, xW1p,
                                            Bfrag + (size_t)l * 2048, nn2_b1 + l * 64, Hsum16, N);
        k_node<<<nb64, 256, 0, stream>>>(Hsum16, xA_cur, deg, batch,
                                         Ff + (size_t)l * 4096, pb + l * 64, nn1_b1 + l * 64, eps,
                                         Ff + (size_t)(5 + (has_next ? l : 0)) * 4096, qb + (has_next ? l : 0) * 64, xW1p,
                                         Ff + (size_t)(9 + (has_next ? l : 0)) * 4096, rb + (has_next ? l : 0) * 64, xA_nxt,
                                         hpool + (size_t)l * G * 64, N, has_next);
        float* tmp = xA_cur; xA_cur = xA_nxt; xA_nxt = tmp;
    }

    k_pool_final<<<G, 320, 0, stream>>>(hpool, cnt, nn1_w2, nn1_b2,
                                        fin_w1, fin_b1, fin_w2, fin_b2, (float*)d_out, G);
}